// Round 1
// 979.584 us; speedup vs baseline: 1.8482x; 1.8482x over previous
//
#include <hip/hip_runtime.h>
#include <hip/hip_bf16.h>
#include <hip/hip_fp16.h>

using bf16 = __hip_bfloat16;
static __device__ __forceinline__ float b2f(bf16 v) { return __bfloat162float(v); }

// dtype-flexible scalar load: f32 ? fp32 : bf16
static __device__ __forceinline__ float dld(const void* p, size_t i, bool f32) {
    return f32 ? ((const float*)p)[i] : b2f(((const bf16*)p)[i]);
}

static __device__ __forceinline__ float ldf(const float* p, size_t i) { return p[i]; }
static __device__ __forceinline__ float ldf(const __half* p, size_t i) { return __half2float(p[i]); }
static __device__ __forceinline__ void stf(float* p, size_t i, float v) { p[i] = v; }
static __device__ __forceinline__ void stf(__half* p, size_t i, float v) { p[i] = __float2half(v); }

#define PI4f 0.78539816339744830961f

// ---------------------------------------------------------------------------
// Input-dtype detection (flag=1.0 -> fp32, 0.0 -> bf16).
// ---------------------------------------------------------------------------
__global__ void detect_k(const unsigned short* __restrict__ xu,
                         float* __restrict__ flag) {
    __shared__ int sh[256];
    int tid = threadIdx.x;
    int cnt = 0;
    for (int i = tid; i < 4096; i += 256) {
        int e = (xu[i] >> 7) & 0xFF;
        if (e < 96 || e > 160) cnt++;
    }
    sh[tid] = cnt;
    __syncthreads();
    for (int off = 128; off > 0; off >>= 1) {
        if (tid < off) sh[tid] += sh[tid + off];
        __syncthreads();
    }
    if (tid == 0) flag[0] = (sh[0] > 64) ? 1.f : 0.f;
}

__global__ void zero_k(float* __restrict__ p, int n) {
    int i = threadIdx.x;
    if (i < n) p[i] = 0.f;
}

// grid-stride-free float4 zero for the y1/y2/y3 accumulation buffers
__global__ void zeroN_k(float4* __restrict__ p, int n4) {
    int i = blockIdx.x * 256 + threadIdx.x;
    if (i < n4) p[i] = make_float4(0.f, 0.f, 0.f, 0.f);
}

// ---------------------------------------------------------------------------
// Weight convert -> fp32, TRANSPOSED to [ci][tap][co] so per-(ci,tap) the co
// vector is contiguous (16B-aligned) for wave-uniform loads in the conv
// kernels. Also keeps w00 in native [co][tap] (conv0f y00 phase) and a
// [tap][co] copy (stats00).
// Float offsets in WF block: wf00:0(432) wf00t:432(432) wf0t:864(13824)
// wf1t:14688(55296) wf2t:69984(110592) wf3t:180576(110592) end:291168
// ---------------------------------------------------------------------------
__global__ void wcvt_k(const void* __restrict__ w00, const void* __restrict__ w0,
                       const void* __restrict__ w1, const void* __restrict__ w2,
                       const void* __restrict__ w3, const float* __restrict__ flag,
                       float* __restrict__ dst) {
    const bool f = flag[0] != 0.f;
    int i = blockIdx.x * 256 + threadIdx.x;
    if (i < 432) {
        float v = dld(w00, i, f);
        dst[i] = v;
        int co = i / 27, tap = i % 27;
        dst[432 + tap * 16 + co] = v;
    }
    if (i < 13824) {  // w0 [32][16][27] -> [16*27][32]
        float v = dld(w0, i, f);
        int co = i / 432, rem = i % 432, ci = rem / 27, tap = rem % 27;
        dst[864 + (ci * 27 + tap) * 32 + co] = v;
    }
    if (i < 55296) {  // w1 [64][32][27] -> [32*27][64]
        float v = dld(w1, i, f);
        int co = i / 864, rem = i % 864, ci = rem / 27, tap = rem % 27;
        dst[14688 + (ci * 27 + tap) * 64 + co] = v;
    }
    if (i < 110592) {  // w2 [64][64][27] -> [64*27][64]
        float v = dld(w2, i, f);
        int co = i / 1728, rem = i % 1728, ci = rem / 27, tap = rem % 27;
        dst[69984 + (ci * 27 + tap) * 64 + co] = v;
    }
    if (i < 110592) {  // w3 [64][64][27] -> [64*27][64]
        float v = dld(w3, i, f);
        int co = i / 1728, rem = i % 1728, ci = rem / 27, tap = rem % 27;
        dst[180576 + (ci * 27 + tap) * 64 + co] = v;
    }
}

// ---------------------------------------------------------------------------
// conv00 stats, LDS-tiled: stage an 18^3 x-tile, compute conv00 for a 16^3
// region x 16 channels in registers, reduce {sum,sumsq} per channel.
// ---------------------------------------------------------------------------
template <bool F32>
__device__ __forceinline__ void stats00_body(const void* __restrict__ xv,
                                             const float* __restrict__ wf00t,
                                             const void* __restrict__ b00,
                                             float* __restrict__ sums,
                                             float* xt, float* rs, float* rq) {
    const int tid = threadIdx.x;
    const int rbk = blockIdx.x;
    const int rx = rbk & 3, ry = (rbk >> 2) & 3, rz = rbk >> 4;
    const int b = blockIdx.z;
    const int z0 = rz * 16 - 1, y0 = ry * 16 - 1, x0 = rx * 16 - 1;
    const size_t xbase = (size_t)b * 262144;

    for (int idx = tid; idx < 5832; idx += 256) {
        int ix = idx % 18;
        int r = idx / 18;
        int iy = r % 18;
        int iz = r / 18;
        int zz = z0 + iz, yy = y0 + iy, xx = x0 + ix;
        float v = 0.f;
        if (zz >= 0 && zz < 64 && yy >= 0 && yy < 64 && xx >= 0 && xx < 64) {
            size_t gi = xbase + ((size_t)zz * 64 + yy) * 64 + xx;
            v = F32 ? ((const float*)xv)[gi] : b2f(((const bf16*)xv)[gi]);
        }
        xt[idx] = v;
    }
    if (tid < 16) { rs[tid] = 0.f; rq[tid] = 0.f; }
    __syncthreads();

    float bia[16];
#pragma unroll
    for (int c = 0; c < 16; c++) bia[c] = dld(b00, c, F32);
    float s[16], sq[16];
#pragma unroll
    for (int c = 0; c < 16; c++) { s[c] = 0.f; sq[c] = 0.f; }

    for (int k = 0; k < 16; k++) {
        int v = tid + k * 256;
        int z = v >> 8, y = (v >> 4) & 15, xw = v & 15;
        float oc[16];
#pragma unroll
        for (int c = 0; c < 16; c++) oc[c] = bia[c];
#pragma unroll
        for (int kz = 0; kz < 3; kz++)
#pragma unroll
        for (int ky = 0; ky < 3; ky++)
#pragma unroll
        for (int kx = 0; kx < 3; kx++) {
            float a = xt[(z + kz) * 324 + (y + ky) * 18 + (xw + kx)];
            const float4* w4 = (const float4*)(wf00t + ((kz * 3 + ky) * 3 + kx) * 16);
#pragma unroll
            for (int j = 0; j < 4; j++) {
                float4 wv = w4[j];
                oc[4 * j + 0] += a * wv.x;
                oc[4 * j + 1] += a * wv.y;
                oc[4 * j + 2] += a * wv.z;
                oc[4 * j + 3] += a * wv.w;
            }
        }
#pragma unroll
        for (int c = 0; c < 16; c++) { s[c] += oc[c]; sq[c] += oc[c] * oc[c]; }
    }
    const int lane = tid & 63;
#pragma unroll
    for (int c = 0; c < 16; c++) {
        float v1 = s[c], v2 = sq[c];
#pragma unroll
        for (int off = 32; off > 0; off >>= 1) {
            v1 += __shfl_down(v1, off, 64);
            v2 += __shfl_down(v2, off, 64);
        }
        if (lane == 0) { atomicAdd(&rs[c], v1); atomicAdd(&rq[c], v2); }
    }
    __syncthreads();
    if (tid < 16) {
        atomicAdd(&sums[tid], rs[tid]);
        atomicAdd(&sums[16 + tid], rq[tid]);
    }
}

__launch_bounds__(256)
__global__ void stats00_k(const void* __restrict__ x, const float* __restrict__ wf00t,
                          const void* __restrict__ b00, const float* __restrict__ flag,
                          float* __restrict__ sums) {
    __shared__ float xt[5832];
    __shared__ float rs[16], rq[16];
    if (flag[0] != 0.f) stats00_body<true>(x, wf00t, b00, sums, xt, rs, rq);
    else                stats00_body<false>(x, wf00t, b00, sums, xt, rs, rq);
}

// ---------------------------------------------------------------------------
// Fused conv0: recompute y00 tile (conv00 + BN(stats00) + ReLU) from x in LDS,
// then stride-2 conv0 over 32 output channels.
// yt rows stored EVEN/ODD-split: col = x/2 + (x&1)*9, row stride 18. Stride-2
// tap reads become stride-1 in ox -> banks (4*oy+ox)%32 = 2 lanes/bank (free),
// vs 4-way conflict of the plain layout (SQ_LDS_BANK_CONFLICT was 8.25e7).
// ---------------------------------------------------------------------------
template <bool F32, typename TOUT>
__device__ __forceinline__ void conv0f_body(
    const void* __restrict__ xv, const float* __restrict__ wf00,
    const void* __restrict__ b00, const float* __restrict__ wf0t,
    const void* __restrict__ b0v, const void* __restrict__ g00,
    const void* __restrict__ be00, const float* __restrict__ sums00,
    TOUT* __restrict__ y0, float* xt, float* yt) {
    constexpr int YTXP = 18;                      // padded row stride
    constexpr int YROW = 17 * YTXP;               // padded z-slice stride (306)
    constexpr int YTOT = 9 * 17 * 17;             // logical elems 2601
    constexpr int XTY = 19, XTX = 19, XTOT = 11 * 19 * 19;  // 3971

    const int tid = threadIdx.x;
    const int tbk = blockIdx.x;  // 4 x 4 x 8 tiles
    const int tx = tbk & 3;
    const int ty = (tbk >> 2) & 3;
    const int tz = tbk >> 4;
    const int b = blockIdx.z;

    const int ox = tid & 7, oy = (tid >> 3) & 7, oz = tid >> 6;
    const int gz = tz * 4 + oz, gy = ty * 8 + oy, gx = tx * 8 + ox;

    const int iz0 = tz * 8 - 1, iy0 = ty * 16 - 1, ix0 = tx * 16 - 1;
    const int xz0 = iz0 - 1, xy0 = iy0 - 1, xx0 = ix0 - 1;

    const size_t xbase = (size_t)b * 262144;
    for (int idx = tid; idx < XTOT; idx += 256) {
        int ix = idx % XTX;
        int r = idx / XTX;
        int iy = r % XTY;
        int iz = r / XTY;
        int zz = xz0 + iz, yy = xy0 + iy, xx = xx0 + ix;
        float v = 0.f;
        if (zz >= 0 && zz < 64 && yy >= 0 && yy < 64 && xx >= 0 && xx < 64) {
            size_t gi = xbase + ((size_t)zz * 64 + yy) * 64 + xx;
            v = F32 ? ((const float*)xv)[gi] : b2f(((const bf16*)xv)[gi]);
        }
        xt[idx] = v;
    }

    float acc[32];
#pragma unroll
    for (int i = 0; i < 32; i++) acc[i] = 0.f;

    for (int ci = 0; ci < 16; ci++) {
        float mean = sums00[ci] * (1.f / 4194304.f);
        float var = sums00[16 + ci] * (1.f / 4194304.f) - mean * mean;
        float A = dld(g00, ci, F32) * rsqrtf(var + 1e-5f);
        float Bs = dld(be00, ci, F32) - mean * A;
        const float* wrp = wf00 + ci * 27;  // uniform
        const float bia = dld(b00, ci, F32);
        __syncthreads();  // prev iter's yt reads done before overwriting
        for (int idx = tid; idx < YTOT; idx += 256) {
            int ix = idx % 17;
            int r = idx / 17;
            int iy = r % 17;
            int iz = r / 17;
            int zz = iz0 + iz, yy = iy0 + iy, xx = ix0 + ix;
            float v = 0.f;
            if (zz >= 0 && zz < 64 && yy >= 0 && yy < 64 && xx >= 0 && xx < 64) {
                float o = bia;
#pragma unroll
                for (int kz = 0; kz < 3; kz++)
#pragma unroll
                for (int ky = 0; ky < 3; ky++)
#pragma unroll
                for (int kx = 0; kx < 3; kx++)
                    o += xt[(iz + kz) * (XTY * XTX) + (iy + ky) * XTX + (ix + kx)] *
                         wrp[(kz * 3 + ky) * 3 + kx];
                v = fmaxf(0.f, A * o + Bs);
            }
            yt[iz * YROW + iy * YTXP + ((ix >> 1) + (ix & 1) * 9)] = v;
        }
        __syncthreads();
#pragma unroll
        for (int kz = 0; kz < 3; kz++)
#pragma unroll
        for (int ky = 0; ky < 3; ky++)
#pragma unroll
        for (int kx = 0; kx < 3; kx++) {
            const int xcol = (kx & 1) ? (9 + ox) : (ox + (kx >> 1));
            float a = yt[(oz * 2 + kz) * YROW + (oy * 2 + ky) * YTXP + xcol];
            const int tap = (kz * 3 + ky) * 3 + kx;
            const float4* wp4 = (const float4*)(wf0t + (ci * 27 + tap) * 32);
#pragma unroll
            for (int j = 0; j < 8; j++) {
                float4 wv = wp4[j];
                acc[4 * j + 0] += a * wv.x;
                acc[4 * j + 1] += a * wv.y;
                acc[4 * j + 2] += a * wv.z;
                acc[4 * j + 3] += a * wv.w;
            }
        }
    }
    const size_t outSp = 32768;
    const size_t obase = ((size_t)b * 32) * outSp + ((size_t)gz * 32 + gy) * 32 + gx;
#pragma unroll
    for (int co = 0; co < 32; co++)
        stf(y0, obase + (size_t)co * outSp, acc[co] + dld(b0v, co, F32));
}

template <typename TOUT>
__launch_bounds__(256)
__global__ void conv0f_k(const void* __restrict__ x, const float* __restrict__ wf00,
                         const void* __restrict__ b00, const float* __restrict__ wf0t,
                         const void* __restrict__ b0v, const void* __restrict__ g00,
                         const void* __restrict__ be00,
                         const float* __restrict__ sums00,
                         const float* __restrict__ flag, TOUT* __restrict__ y0) {
    __shared__ float xt[11 * 19 * 19];
    __shared__ float yt[9 * 17 * 18];
    if (flag[0] != 0.f)
        conv0f_body<true>(x, wf00, b00, wf0t, b0v, g00, be00, sums00, y0, xt, yt);
    else
        conv0f_body<false>(x, wf00, b00, wf0t, b0v, g00, be00, sums00, y0, xt, yt);
}

// ---------------------------------------------------------------------------
// ci-SPLIT direct 3D conv (k=3, pad=1, stride 2), prev-layer BN+ReLU fused at
// tile load. The CIN loop is partitioned across NCHUNK blocks (blockIdx.y
// carries co-group * chunk); partial sums are accumulated with atomicAdd into
// a pre-zeroed output. This fixes the latency collapse of the old monolithic
// kernel (conv2: 256 blocks x 2 waves, 5.7% occupancy, 64 serial ci iters,
// 417 us for 1.8 GFLOP).
// LDS tile rows stored even/odd-split like conv0f (free-conflict tap reads).
// ---------------------------------------------------------------------------
template <typename TIN, int CIN, int COUT, int COACC, int NCHUNK, int TZ, int TY,
          int TX, int STRIDE, int IND, int OUTD>
__launch_bounds__(TZ * TY * TX)
__global__ void convsplit_k(const TIN* __restrict__ inv,
                            const float* __restrict__ wft,  // [CIN*27][COUT]
                            const void* __restrict__ bias,
                            const void* __restrict__ g_prev,
                            const void* __restrict__ be_prev,
                            const float* __restrict__ stats_prev,  // [2*CIN]
                            float Ninv_prev, const float* __restrict__ flag,
                            float* __restrict__ out) {
    static_assert(STRIDE == 2, "even/odd tile layout assumes stride 2");
    constexpr int NT = TZ * TY * TX;
    constexpr int ITZ = (TZ - 1) * STRIDE + 3;
    constexpr int ITY = (TY - 1) * STRIDE + 3;
    constexpr int ITX = (TX - 1) * STRIDE + 3;
    constexpr int ITXP = ITX + 1;
    constexpr int HALF = (ITX + 1) / 2;  // even/odd split point
    constexpr int ITOT = ITZ * ITY * ITX;
    constexpr int NTX = OUTD / TX, NTY = OUTD / TY;
    constexpr int CICH = CIN / NCHUNK;
    constexpr int NCO = COUT / COACC;

    __shared__ float tile[ITZ * ITY * ITXP];

    const bool F = flag[0] != 0.f;
    const int tid = threadIdx.x;
    const int tbk = blockIdx.x;
    const int tx = tbk % NTX;
    const int t2 = tbk / NTX;
    const int ty = t2 % NTY;
    const int tz = t2 / NTY;
    const int coBase = (blockIdx.y % NCO) * COACC;
    const int chunk = blockIdx.y / NCO;
    const int b = blockIdx.z;

    const int ox = tid % TX;
    const int oy = (tid / TX) % TY;
    const int oz = tid / (TX * TY);
    const int gz = tz * TZ + oz, gy = ty * TY + oy, gx = tx * TX + ox;

    float acc[COACC];
#pragma unroll
    for (int i = 0; i < COACC; i++) acc[i] = 0.f;

    const int iz0 = tz * TZ * STRIDE - 1;
    const int iy0 = ty * TY * STRIDE - 1;
    const int ix0 = tx * TX * STRIDE - 1;

    for (int ci = chunk * CICH; ci < (chunk + 1) * CICH; ci++) {
        float mean = stats_prev[ci] * Ninv_prev;
        float var = stats_prev[CIN + ci] * Ninv_prev - mean * mean;
        float A = dld(g_prev, ci, F) * rsqrtf(var + 1e-5f);
        float Bs = dld(be_prev, ci, F) - mean * A;
        __syncthreads();
        const size_t chanBase = ((size_t)(b * CIN + ci)) * IND * IND * IND;
        for (int idx = tid; idx < ITOT; idx += NT) {
            int ix = idx % ITX;
            int r = idx / ITX;
            int iy = r % ITY;
            int iz = r / ITY;
            int zz = iz0 + iz, yy = iy0 + iy, xx = ix0 + ix;
            float v = 0.f;
            if (zz >= 0 && zz < IND && yy >= 0 && yy < IND && xx >= 0 && xx < IND) {
                float raw = ldf(inv, chanBase + ((size_t)zz * IND + yy) * IND + xx);
                v = fmaxf(0.f, A * raw + Bs);
            }
            tile[(iz * ITY + iy) * ITXP + ((ix >> 1) + (ix & 1) * HALF)] = v;
        }
        __syncthreads();
#pragma unroll
        for (int kz = 0; kz < 3; kz++)
#pragma unroll
        for (int ky = 0; ky < 3; ky++)
#pragma unroll
        for (int kx = 0; kx < 3; kx++) {
            const int xcol = (kx & 1) ? (HALF + ox) : (ox + (kx >> 1));
            float a = tile[((oz * STRIDE + kz) * ITY + (oy * STRIDE + ky)) * ITXP +
                           xcol];
            const int tap = (kz * 3 + ky) * 3 + kx;
            const float4* wp4 =
                (const float4*)(wft + (size_t)(ci * 27 + tap) * COUT + coBase);
#pragma unroll
            for (int j = 0; j < COACC / 4; j++) {
                float4 wv = wp4[j];
                acc[4 * j + 0] += a * wv.x;
                acc[4 * j + 1] += a * wv.y;
                acc[4 * j + 2] += a * wv.z;
                acc[4 * j + 3] += a * wv.w;
            }
        }
    }
    const size_t outSp = (size_t)OUTD * OUTD * OUTD;
    const size_t obase = ((size_t)b * COUT + coBase) * outSp +
                         ((size_t)gz * OUTD + gy) * OUTD + gx;
#pragma unroll
    for (int co = 0; co < COACC; co++) {
        float v = acc[co];
        if (chunk == 0) v += dld(bias, coBase + co, F);
        atomicAdd(&out[obase + (size_t)co * outSp], v);
    }
}

// ---------------------------------------------------------------------------
// Per-channel {sum,sumsq}; grid=(C,K); sums layout [C sums][C sumsqs].
// ---------------------------------------------------------------------------
template <typename T>
__global__ void stats_k(const T* __restrict__ raw, float* __restrict__ sums,
                        int C, int spatial, int B) {
    const int c = blockIdx.x;
    const int K = gridDim.y;
    const int part = blockIdx.y;
    float s = 0.f, sq = 0.f;
    for (int b = 0; b < B; b++) {
        const T* p = raw + ((size_t)(b * C + c)) * spatial;
        if constexpr (sizeof(T) == 4) {
            const float4* p4 = (const float4*)p;
            for (int i = part * blockDim.x + threadIdx.x; i < (spatial >> 2);
                 i += K * blockDim.x) {
                float4 v = p4[i];
                s += v.x + v.y + v.z + v.w;
                sq += v.x * v.x + v.y * v.y + v.z * v.z + v.w * v.w;
            }
        } else {
            for (int i = part * blockDim.x + threadIdx.x; i < spatial;
                 i += K * blockDim.x) {
                float v = ldf(p, i);
                s += v;
                sq += v * v;
            }
        }
    }
    __shared__ float rs[256], rq[256];
    int tid = threadIdx.x;
    rs[tid] = s;
    rq[tid] = sq;
    __syncthreads();
    for (int off = blockDim.x / 2; off > 0; off >>= 1) {
        if (tid < off) { rs[tid] += rs[tid + off]; rq[tid] += rq[tid + off]; }
        __syncthreads();
    }
    if (tid == 0) {
        atomicAdd(&sums[c], rs[0]);
        atomicAdd(&sums[C + c], rq[0]);
    }
}

// ---------------------------------------------------------------------------
// FC heads + affine matrix chain. One block per batch.
// ---------------------------------------------------------------------------
static __device__ __forceinline__ void mm4(const float* A, const float* B, float* C) {
    for (int i = 0; i < 4; i++)
        for (int j = 0; j < 4; j++) {
            float s = 0.f;
            for (int k = 0; k < 4; k++) s += A[i * 4 + k] * B[k * 4 + j];
            C[i * 4 + j] = s;
        }
}
static __device__ __forceinline__ void ident(float* M) {
    for (int i = 0; i < 16; i++) M[i] = (i % 5 == 0) ? 1.f : 0.f;
}

__global__ void fc_affine_k(const float* __restrict__ y3,
                            const float* __restrict__ stats3,
                            const void* __restrict__ g3, const void* __restrict__ be3,
                            const void* __restrict__ tw, const void* __restrict__ tbv,
                            const void* __restrict__ rw, const void* __restrict__ rbv,
                            const void* __restrict__ sw, const void* __restrict__ sbv,
                            const void* __restrict__ shw, const void* __restrict__ shbv,
                            const float* __restrict__ flag,
                            float* __restrict__ theta) {
    const bool F = flag[0] != 0.f;
    const int b = blockIdx.x;
    const int tid = threadIdx.x;
    __shared__ float Ab[64], Bb[64];
    if (tid < 64) {
        float mean = stats3[tid] * (1.f / 1024.f);
        float var = stats3[64 + tid] * (1.f / 1024.f) - mean * mean;
        float A = dld(g3, tid, F) * rsqrtf(var + 1e-5f);
        Ab[tid] = A;
        Bb[tid] = dld(be3, tid, F) - mean * A;
    }
    __syncthreads();
    float acc[12];
#pragma unroll
    for (int j = 0; j < 12; j++) acc[j] = 0.f;
    const float* yb = y3 + (size_t)b * 4096;
    for (int f = tid; f < 4096; f += 256) {
        int c = f >> 6;
        float x = fmaxf(0.f, Ab[c] * yb[f] + Bb[c]);
#pragma unroll
        for (int i = 0; i < 3; i++) {
            acc[0 + i] += x * dld(tw, i * 4096 + f, F);
            acc[3 + i] += x * dld(rw, i * 4096 + f, F);
            acc[6 + i] += x * dld(sw, i * 4096 + f, F);
            acc[9 + i] += x * dld(shw, i * 4096 + f, F);
        }
    }
    __shared__ float red[256];
    __shared__ float dots[12];
    for (int j = 0; j < 12; j++) {
        red[tid] = acc[j];
        __syncthreads();
        for (int off = 128; off > 0; off >>= 1) {
            if (tid < off) red[tid] += red[tid + off];
            __syncthreads();
        }
        if (tid == 0) dots[j] = red[0];
        __syncthreads();
    }
    if (tid == 0) {
        float trans[3], rot[3], scl[3], sh[3];
        for (int i = 0; i < 3; i++) {
            trans[i] = 0.1f * tanhf(dots[0 + i] + dld(tbv, i, F));
            rot[i]   = PI4f * tanhf(dots[3 + i] + dld(rbv, i, F));
            scl[i]   = 0.2f * tanhf(dots[6 + i] + dld(sbv, i, F));
            sh[i]    = PI4f * tanhf(dots[9 + i] + dld(shbv, i, F));
        }
        float T[16], R1[16], R2[16], R3[16], S[16], H1[16], H2[16], H3[16];
        float t1[16], t2[16], R[16], Sh[16], ShT[16], M[16];
        ident(T); T[3] = trans[0]; T[7] = trans[1]; T[11] = trans[2];
        { float c = cosf(rot[0]), s = sinf(rot[0]);
          ident(R1); R1[0] = c; R1[1] = -s; R1[4] = s; R1[5] = c; }
        { float c = cosf(rot[1]), s = sinf(rot[1]);
          ident(R2); R2[5] = c; R2[6] = -s; R2[9] = s; R2[10] = c; }
        { float c = cosf(rot[2]), s = sinf(rot[2]);
          ident(R3); R3[0] = c; R3[1] = -s; R3[4] = s; R3[5] = c; }
        mm4(R1, R2, t1); mm4(t1, R3, R);
        ident(S); S[0] = expf(scl[0]); S[5] = expf(scl[1]); S[10] = expf(scl[2]);
        { float c = cosf(sh[0]), s = sinf(sh[0]);
          ident(H1); H1[5] = c; H1[6] = -s; H1[9] = s; H1[10] = c; }
        { float c = cosf(sh[1]), s = sinf(sh[1]);
          ident(H2); H2[0] = c; H2[2] = s; H2[8] = -s; H2[10] = c; }
        { float c = cosf(sh[2]), s = sinf(sh[2]);
          ident(H3); H3[0] = c; H3[1] = -s; H3[4] = s; H3[5] = c; }
        mm4(H1, H2, t1); mm4(t1, H3, Sh);
        for (int i = 0; i < 4; i++)
            for (int j = 0; j < 4; j++) ShT[i * 4 + j] = Sh[j * 4 + i];
        mm4(Sh, S, t1); mm4(t1, ShT, t2); mm4(t2, R, t1); mm4(t1, T, M);
        for (int i = 0; i < 12; i++) theta[b * 12 + i] = M[i];
    }
}

// ---------------------------------------------------------------------------
// Trilinear grid sample (zero padding, reference corner semantics).
// ---------------------------------------------------------------------------
template <bool F32>
__device__ __forceinline__ void sample_body(const void* __restrict__ xv,
                                            const float* __restrict__ theta,
                                            void* __restrict__ out) {
    const int b = blockIdx.y;
    const int v = blockIdx.x * 256 + threadIdx.x;
    const int w = v & 63, h = (v >> 6) & 63, d = v >> 12;
    const float* t = theta + b * 12;
    const float px = -1.f + w * (2.f / 63.f);
    const float py = -1.f + h * (2.f / 63.f);
    const float pz = -1.f + d * (2.f / 63.f);
    const float gx = t[0] * px + t[1] * py + t[2] * pz + t[3];
    const float gy = t[4] * px + t[5] * py + t[6] * pz + t[7];
    const float gz = t[8] * px + t[9] * py + t[10] * pz + t[11];
    const float fx = ((gx + 1.f) * 64.f - 1.f) * 0.5f;
    const float fy = ((gy + 1.f) * 64.f - 1.f) * 0.5f;
    const float fz = ((gz + 1.f) * 64.f - 1.f) * 0.5f;
    const float x0 = floorf(fx), y0 = floorf(fy), z0 = floorf(fz);
    const float wx1 = fx - x0, wy1 = fy - y0, wz1 = fz - z0;
    const size_t ibase = (size_t)b * 262144;
    float outv = 0.f;
#pragma unroll
    for (int dz = 0; dz < 2; dz++) {
        float wz = dz ? wz1 : 1.f - wz1;
        int zc = (int)z0 + dz;
        bool zok = (zc >= 0 && zc < 64);
        int zi = min(max(zc, 0), 63);
#pragma unroll
        for (int dy = 0; dy < 2; dy++) {
            float wy = dy ? wy1 : 1.f - wy1;
            int yc = (int)y0 + dy;
            bool yok = (yc >= 0 && yc < 64);
            int yi = min(max(yc, 0), 63);
#pragma unroll
            for (int dx = 0; dx < 2; dx++) {
                float wwx = dx ? wx1 : 1.f - wx1;
                int xc = (int)x0 + dx;
                bool xok = (xc >= 0 && xc < 64);
                int xi = min(max(xc, 0), 63);
                size_t gi = ibase + ((size_t)zi * 64 + yi) * 64 + xi;
                float val = F32 ? ((const float*)xv)[gi] : b2f(((const bf16*)xv)[gi]);
                float wgt = (zok && yok && xok) ? wz * wy * wwx : 0.f;
                outv += val * wgt;
            }
        }
    }
    const size_t oi = (size_t)b * 262144 + v;
    if (F32) ((float*)out)[oi] = outv;
    else ((bf16*)out)[oi] = __float2bfloat16(outv);
}

__global__ void sample_k(const void* __restrict__ x, const float* __restrict__ theta,
                         const float* __restrict__ flag, void* __restrict__ out) {
    if (flag[0] != 0.f) sample_body<true>(x, theta, out);
    else                sample_body<false>(x, theta, out);
}

// ---------------------------------------------------------------------------
// Host launcher
// ---------------------------------------------------------------------------
extern "C" void kernel_launch(void* const* d_in, const int* in_sizes, int n_in,
                              void* d_out, int out_size, void* d_ws, size_t ws_size,
                              hipStream_t stream) {
    const void* x    = d_in[0];
    const void* w00  = d_in[1];
    const void* b00  = d_in[2];
    const void* g00  = d_in[3];
    const void* be00 = d_in[4];
    const void* w0   = d_in[5];
    const void* b0   = d_in[6];
    const void* g0   = d_in[7];
    const void* be0  = d_in[8];
    const void* w1   = d_in[9];
    const void* b1   = d_in[10];
    const void* g1   = d_in[11];
    const void* be1  = d_in[12];
    const void* w2   = d_in[13];
    const void* b2   = d_in[14];
    const void* g2   = d_in[15];
    const void* be2  = d_in[16];
    const void* w3   = d_in[17];
    const void* b3   = d_in[18];
    const void* g3   = d_in[19];
    const void* be3  = d_in[20];
    const void* tw   = d_in[21];
    const void* tb   = d_in[22];
    const void* rw   = d_in[23];
    const void* rb   = d_in[24];
    const void* sw   = d_in[25];
    const void* sb   = d_in[26];
    const void* shw  = d_in[27];
    const void* shb  = d_in[28];

    float* wsF = (float*)d_ws;
    const bool f32path = ws_size >= (size_t)21853232 * 4;
    const size_t Y0U = f32path ? 16777216 : 8388608;  // float-units for y0
    const size_t Y1_OFF = Y0U;
    const size_t Y2_OFF = Y1_OFF + 4194304;
    const size_t Y3_OFF = Y2_OFF + 524288;
    const size_t WF_OFF = Y3_OFF + 65536;
    const size_t ST_OFF = WF_OFF + 291200;
    const size_t FL_OFF = ST_OFF + 480;
    const size_t TH_OFF = ST_OFF + 496;

    float* y1 = wsF + Y1_OFF;
    float* y2 = wsF + Y2_OFF;
    float* y3 = wsF + Y3_OFF;
    float* wf00  = wsF + WF_OFF + 0;
    float* wf00t = wsF + WF_OFF + 432;
    float* wf0t  = wsF + WF_OFF + 864;
    float* wf1t  = wsF + WF_OFF + 14688;
    float* wf2t  = wsF + WF_OFF + 69984;
    float* wf3t  = wsF + WF_OFF + 180576;
    float* sums00 = wsF + ST_OFF + 0;    // 32
    float* sums0  = wsF + ST_OFF + 32;   // 64
    float* sums1  = wsF + ST_OFF + 96;   // 128
    float* sums2  = wsF + ST_OFF + 224;  // 128
    float* sums3  = wsF + ST_OFF + 352;  // 128
    float* flag   = wsF + FL_OFF;        // 1
    float* theta  = wsF + TH_OFF;        // 192

    zero_k<<<1, 512, 0, stream>>>(wsF + ST_OFF, 480);
    // zero y1|y2|y3 (contiguous, 4194304+524288+65536 = 4784128 floats) for
    // the ci-split atomic accumulation
    zeroN_k<<<4672, 256, 0, stream>>>((float4*)y1, 1196032);
    detect_k<<<1, 256, 0, stream>>>((const unsigned short*)x, flag);
    wcvt_k<<<432, 256, 0, stream>>>(w00, w0, w1, w2, w3, flag, wsF + WF_OFF);

    stats00_k<<<dim3(64, 1, 16), 256, 0, stream>>>(x, wf00t, b00, flag, sums00);

    if (f32path) {
        float* y0 = wsF;
        conv0f_k<float><<<dim3(128, 1, 16), 256, 0, stream>>>(
            x, wf00, b00, wf0t, b0, g00, be00, sums00, flag, y0);
        stats_k<float><<<dim3(32, 32), 256, 0, stream>>>(y0, sums0, 32, 32768, 16);
        // conv1: 32ci -> 64co, 32^3 -> 16^3; ci split x2 (1024 blocks, 16 serial ci)
        convsplit_k<float, 32, 64, 32, 2, 4, 8, 8, 2, 32, 16>
            <<<dim3(16, 4, 16), 256, 0, stream>>>(y0, wf1t, b1, g0, be0, sums0,
                                                  1.f / 524288.f, flag, y1);
    } else {
        __half* y0 = (__half*)d_ws;
        conv0f_k<__half><<<dim3(128, 1, 16), 256, 0, stream>>>(
            x, wf00, b00, wf0t, b0, g00, be00, sums00, flag, y0);
        stats_k<__half><<<dim3(32, 32), 256, 0, stream>>>(y0, sums0, 32, 32768, 16);
        convsplit_k<__half, 32, 64, 32, 2, 4, 8, 8, 2, 32, 16>
            <<<dim3(16, 4, 16), 256, 0, stream>>>(y0, wf1t, b1, g0, be0, sums0,
                                                  1.f / 524288.f, flag, y1);
    }

    stats_k<float><<<dim3(64, 4), 256, 0, stream>>>(y1, sums1, 64, 4096, 16);

    // conv2: 64ci -> 64co, 16^3 -> 8^3; ci split x8 (2048 blocks, 8 serial ci)
    convsplit_k<float, 64, 64, 16, 8, 2, 8, 8, 2, 16, 8>
        <<<dim3(4, 32, 16), 128, 0, stream>>>(y1, wf2t, b2, g1, be1, sums1,
                                              1.f / 65536.f, flag, y2);
    stats_k<float><<<dim3(64, 1), 256, 0, stream>>>(y2, sums2, 64, 512, 16);

    // conv3: 64ci -> 64co, 8^3 -> 4^3; ci split x16 (1024 blocks, 4 serial ci)
    convsplit_k<float, 64, 64, 16, 16, 4, 4, 4, 2, 8, 4>
        <<<dim3(1, 64, 16), 64, 0, stream>>>(y2, wf3t, b3, g2, be2, sums2,
                                             1.f / 8192.f, flag, y3);
    stats_k<float><<<dim3(64, 1), 256, 0, stream>>>(y3, sums3, 64, 64, 16);

    fc_affine_k<<<16, 256, 0, stream>>>(y3, sums3, g3, be3, tw, tb, rw, rb, sw, sb,
                                        shw, shb, flag, theta);

    sample_k<<<dim3(1024, 16), 256, 0, stream>>>(x, theta, flag, d_out);
}